// Round 1
// baseline (1289.750 us; speedup 1.0000x reference)
//
#include <hip/hip_runtime.h>
#include <cstdint>
#include <cstddef>

#define B_DIM 8
#define U_DIM 1024
#define S_DIM 1024
#define D_DIM 1024
#define M_DIM (B_DIM * U_DIM)   // 8192

#define BM 128
#define BN 128
#define BK 8

// C[M,N] = A[M,K] @ W[K,N] + bias
// mode 0: A = x*mix_j + shift(x)*(1-mix_j), j = blockIdx.z in {0,1,2}; j==2 applies sigmoid
// mode 1: A = rwkv (plain load), single output (slot k)
__global__ __launch_bounds__(256)
void gemm_fused_kernel(int mode,
    const float* __restrict__ A_,
    const float* __restrict__ mixk,
    const float* __restrict__ mixv,
    const float* __restrict__ mixr,
    const float* __restrict__ Wk, const float* __restrict__ bk_,
    const float* __restrict__ Wv, const float* __restrict__ bv_,
    const float* __restrict__ Wr, const float* __restrict__ br_,
    float* __restrict__ outk, float* __restrict__ outv, float* __restrict__ outr)
{
    __shared__ float As[BK][BM + 4];   // +4 pad: staging writes & b128 reads 2-way max (free)
    __shared__ float Bs[BK][BN];

    const int tid = threadIdx.x;
    const int m0 = blockIdx.x * BM;
    const int n0 = blockIdx.y * BN;

    const float* W; const float* bias; const float* mix; float* out; int dosig = 0;
    if (mode == 1) {
        W = Wk; bias = bk_; mix = nullptr; out = outk;
    } else {
        int j = blockIdx.z;
        if (j == 0)      { W = Wk; bias = bk_; mix = mixk; out = outk; }
        else if (j == 1) { W = Wv; bias = bv_; mix = mixv; out = outv; }
        else             { W = Wr; bias = br_; mix = mixr; out = outr; dosig = 1; }
    }

    // staging indices
    const int ak  = tid & 7;     // k col for A staging
    const int am0 = tid >> 3;    // 32 rows per pass, 4 passes
    const int bn  = tid & 127;   // n col for B staging
    const int bk0 = tid >> 7;    // 2 k rows per pass, 4 passes

    // micro-tile: 8x8 per thread, split 4+4 across the 64-row/col halves
    const int tm = tid & 15;
    const int tn = tid >> 4;

    float acc[8][8];
    #pragma unroll
    for (int i = 0; i < 8; ++i)
        #pragma unroll
        for (int j2 = 0; j2 < 8; ++j2) acc[i][j2] = 0.f;

    for (int k0 = 0; k0 < S_DIM; k0 += BK) {
        // ---- stage A ----
        if (mode == 0) {
            const float mx = mix[k0 + ak];
            #pragma unroll
            for (int p = 0; p < 4; ++p) {
                const int m = m0 + am0 + p * 32;
                const float xv = A_[(size_t)m * S_DIM + k0 + ak];
                const float sh = (m & (U_DIM - 1)) ? A_[(size_t)(m - 1) * S_DIM + k0 + ak] : 0.f;
                As[ak][am0 + p * 32] = sh + mx * (xv - sh);
            }
        } else {
            #pragma unroll
            for (int p = 0; p < 4; ++p) {
                const int m = m0 + am0 + p * 32;
                As[ak][am0 + p * 32] = A_[(size_t)m * S_DIM + k0 + ak];
            }
        }
        // ---- stage B ----
        #pragma unroll
        for (int p = 0; p < 4; ++p) {
            const int kr = bk0 + p * 2;
            Bs[kr][bn] = W[(size_t)(k0 + kr) * D_DIM + n0 + bn];
        }
        __syncthreads();

        #pragma unroll
        for (int kk = 0; kk < BK; ++kk) {
            const float4 aL = *(const float4*)&As[kk][tm * 4];
            const float4 aH = *(const float4*)&As[kk][64 + tm * 4];
            const float4 bL = *(const float4*)&Bs[kk][tn * 4];
            const float4 bH = *(const float4*)&Bs[kk][64 + tn * 4];
            const float av[8] = {aL.x, aL.y, aL.z, aL.w, aH.x, aH.y, aH.z, aH.w};
            const float bw[8] = {bL.x, bL.y, bL.z, bL.w, bH.x, bH.y, bH.z, bH.w};
            #pragma unroll
            for (int i = 0; i < 8; ++i)
                #pragma unroll
                for (int j2 = 0; j2 < 8; ++j2)
                    acc[i][j2] = fmaf(av[i], bw[j2], acc[i][j2]);
        }
        __syncthreads();
    }

    // ---- epilogue: bias (+ sigmoid), float4 stores ----
    #pragma unroll
    for (int ih = 0; ih < 2; ++ih) {
        #pragma unroll
        for (int i = 0; i < 4; ++i) {
            const int m = m0 + ih * 64 + tm * 4 + i;
            #pragma unroll
            for (int jh = 0; jh < 2; ++jh) {
                const int n = n0 + jh * 64 + tn * 4;
                float4 c;
                c.x = acc[ih * 4 + i][jh * 4 + 0] + bias[n + 0];
                c.y = acc[ih * 4 + i][jh * 4 + 1] + bias[n + 1];
                c.z = acc[ih * 4 + i][jh * 4 + 2] + bias[n + 2];
                c.w = acc[ih * 4 + i][jh * 4 + 3] + bias[n + 3];
                if (dosig) {
                    c.x = 1.f / (1.f + __expf(-c.x));
                    c.y = 1.f / (1.f + __expf(-c.y));
                    c.z = 1.f / (1.f + __expf(-c.z));
                    c.w = 1.f / (1.f + __expf(-c.w));
                }
                *(float4*)&out[(size_t)m * D_DIM + n] = c;
            }
        }
    }
}

// WKV recurrence: one thread per (b,d) channel, sequential over U.
// 4-deep register prefetch ring (statically indexed via full unroll).
// rq/rw may alias (rw written only after rq[t] consumed, same thread owns column).
__global__ __launch_bounds__(64)
void wkv_scan_kernel(const float* __restrict__ kq, const float* __restrict__ vq,
                     const float* rq,
                     const float* __restrict__ td, const float* __restrict__ tfirst,
                     float* rw)
{
    const int ch = blockIdx.x * 64 + threadIdx.x;   // 0..8191
    const int b = ch >> 10;
    const int d = ch & (D_DIM - 1);
    const float w  = -__expf(td[d]);
    const float tf = tfirst[d];
    const size_t base = (size_t)b * U_DIM * D_DIM + d;

    float a = 0.f, bden = 0.f, p = -1e38f;

    float kr[4], vr[4], rr[4];
    #pragma unroll
    for (int i = 0; i < 4; ++i) {
        const size_t idx = base + (size_t)i * D_DIM;
        kr[i] = kq[idx]; vr[i] = vq[idx]; rr[i] = rq[idx];
    }

    for (int t = 0; t < U_DIM; t += 4) {
        #pragma unroll
        for (int s = 0; s < 4; ++s) {
            const int tt = t + s;
            const float kt = kr[s], vt = vr[s], rt = rr[s];
            if (tt + 4 < U_DIM) {
                const size_t idx = base + (size_t)(tt + 4) * D_DIM;
                kr[s] = kq[idx]; vr[s] = vq[idx]; rr[s] = rq[idx];
            }
            // output at step tt (time_first bonus on current token)
            const float q  = fmaxf(p, tf + kt);
            const float e1 = __expf(p - q);
            const float e2 = __expf(tf + kt - q);
            const float ov = (e1 * a + e2 * vt) * __builtin_amdgcn_rcpf(e1 * bden + e2);
            // state update (decay by w)
            const float q2  = fmaxf(p + w, kt);
            const float e1b = __expf(p + w - q2);
            const float e2b = __expf(kt - q2);
            a    = e1b * a + e2b * vt;
            bden = e1b * bden + e2b;
            p    = q2;
            rw[base + (size_t)tt * D_DIM] = rt * ov;
        }
    }
}

extern "C" void kernel_launch(void* const* d_in, const int* in_sizes, int n_in,
                              void* d_out, int out_size, void* d_ws, size_t ws_size,
                              hipStream_t stream)
{
    (void)in_sizes; (void)n_in; (void)out_size;
    const float* x  = (const float*)d_in[0];
    const float* td = (const float*)d_in[1];
    const float* tf = (const float*)d_in[2];
    const float* mk = (const float*)d_in[3];
    const float* mv = (const float*)d_in[4];
    const float* mr = (const float*)d_in[5];
    const float* Wk = (const float*)d_in[6];
    const float* bk = (const float*)d_in[7];
    const float* Wv = (const float*)d_in[8];
    const float* bv = (const float*)d_in[9];
    const float* Wr = (const float*)d_in[10];
    const float* br = (const float*)d_in[11];
    const float* Wo = (const float*)d_in[12];
    const float* bo = (const float*)d_in[13];
    float* out = (float*)d_out;

    const size_t NCH = (size_t)M_DIM * D_DIM;   // 8M elements per buffer
    float* kbuf = (float*)d_ws;
    float* vbuf = kbuf + NCH;
    float* rbuf = vbuf + NCH;
    // separate rwkv buffer if workspace allows, else overwrite r in place
    float* rwbuf = (ws_size >= 4 * NCH * sizeof(float)) ? (rbuf + NCH) : rbuf;

    const dim3 blk(256);
    const dim3 g1(M_DIM / BM, D_DIM / BN, 3);
    gemm_fused_kernel<<<g1, blk, 0, stream>>>(0, x, mk, mv, mr,
                                              Wk, bk, Wv, bv, Wr, br,
                                              kbuf, vbuf, rbuf);

    wkv_scan_kernel<<<dim3((B_DIM * D_DIM) / 64), dim3(64), 0, stream>>>(
        kbuf, vbuf, rbuf, td, tf, rwbuf);

    const dim3 g2(M_DIM / BM, S_DIM / BN, 1);
    gemm_fused_kernel<<<g2, blk, 0, stream>>>(1, rwbuf, nullptr, nullptr, nullptr,
                                              Wo, bo, nullptr, nullptr, nullptr, nullptr,
                                              out, nullptr, nullptr);
}

// Round 2
// 183.734 us; speedup vs baseline: 7.0197x; 7.0197x over previous
//
#include <hip/hip_runtime.h>
#include <cstdint>
#include <cstddef>

#define B_DIM 8
#define U_DIM 1024
#define SD    1024                 // SIZE == D_ATT == 1024
#define M_DIM (B_DIM * U_DIM)      // 8192 rows; also B*D channel count
#define NC 32                      // scan chunks
#define CT 32                      // tokens per chunk (NC*CT == U_DIM)

typedef __attribute__((ext_vector_type(8))) short short8;
typedef __attribute__((ext_vector_type(4))) float f32x4;

typedef __attribute__((address_space(3))) void       lds_t;
typedef const __attribute__((address_space(1))) void glb_t;

__device__ __forceinline__ ushort f2bf(float f) {
    union { float f; uint32_t u; } c; c.f = f;
    uint32_t r = (c.u + 0x7FFFu + ((c.u >> 16) & 1u)) >> 16;   // RNE
    return (ushort)r;
}
__device__ __forceinline__ float bf2f(ushort h) {
    union { float f; uint32_t u; } c; c.u = ((uint32_t)h) << 16; return c.f;
}

// ---------------- prepass: W[K][N] f32 -> W^T[N][K] bf16, 4 matrices ----------------
__global__ __launch_bounds__(256)
void wtrans_kernel(const float* __restrict__ Wk, const float* __restrict__ Wv,
                   const float* __restrict__ Wr, const float* __restrict__ Wo,
                   ushort* __restrict__ WT)
{
    __shared__ float t[32][33];
    const float* W = (blockIdx.z == 0) ? Wk : (blockIdx.z == 1) ? Wv
                   : (blockIdx.z == 2) ? Wr : Wo;
    ushort* o = WT + (size_t)blockIdx.z * SD * SD;
    const int tx = threadIdx.x & 31, ty = threadIdx.x >> 5;
    const int k0 = blockIdx.y * 32, n0 = blockIdx.x * 32;
    #pragma unroll
    for (int i = 0; i < 4; ++i)
        t[ty + i * 8][tx] = W[(size_t)(k0 + ty + i * 8) * SD + n0 + tx];
    __syncthreads();
    #pragma unroll
    for (int i = 0; i < 4; ++i)
        o[(size_t)(n0 + ty + i * 8) * SD + k0 + tx] = f2bf(t[tx][ty + i * 8]);
}

// ---------------- prepass: A = sh + mix*(x - sh), bf16 ----------------
__global__ __launch_bounds__(256)
void mix_kernel(const float* __restrict__ x, const float* __restrict__ mix,
                ushort* __restrict__ outA)
{
    const int idx = blockIdx.x * 256 + threadIdx.x;  // 2M groups of 4
    const int m = idx >> 8;
    const int s = (idx & 255) << 2;
    const float4 xv = *(const float4*)&x[(size_t)m * SD + s];
    float4 sh = make_float4(0.f, 0.f, 0.f, 0.f);
    if (m & (U_DIM - 1)) sh = *(const float4*)&x[(size_t)(m - 1) * SD + s];
    const float4 mx = *(const float4*)&mix[s];
    ushort4 o;
    o.x = f2bf(sh.x + mx.x * (xv.x - sh.x));
    o.y = f2bf(sh.y + mx.y * (xv.y - sh.y));
    o.z = f2bf(sh.z + mx.z * (xv.z - sh.z));
    o.w = f2bf(sh.w + mx.w * (xv.w - sh.w));
    *(ushort4*)&outA[(size_t)m * SD + s] = o;
}

// ---------------- bf16 MFMA GEMM: C[M,N] = A[M,K] @ (BT[N,K])^T + bias ----------------
// MODE 0: bf16 out; MODE 1: bf16 out + sigmoid; MODE 2: f32 out
template<int MODE>
__global__ __launch_bounds__(256)
void gemm_bf16(const ushort* __restrict__ A, const ushort* __restrict__ BT,
               const float* __restrict__ bias, void* __restrict__ Cout)
{
    __shared__ ushort As[128 * 32];   // [row][k] row-stride 32 elems (64B)
    __shared__ ushort Bs[128 * 32];   // [n-row][k]

    const int tid = threadIdx.x;
    const int wv = tid >> 6, ln = tid & 63;
    const int m0 = blockIdx.x * 128, n0 = blockIdx.y * 128;
    const int wm = (wv >> 1) * 64, wn = (wv & 1) * 64;

    f32x4 acc[4][4];
    #pragma unroll
    for (int i = 0; i < 4; ++i)
        #pragma unroll
        for (int j = 0; j < 4; ++j)
            acc[i][j] = (f32x4){0.f, 0.f, 0.f, 0.f};

    // staging map: chunk c (16B) -> row = c>>2, kgroup = c&3; lds byte = c*16
    const int rowA = tid >> 2;       // 0..63  (+64 on second issue)
    const int kg   = tid & 3;
    const size_t gA = (size_t)(m0 + rowA) * SD + kg * 8;
    const size_t gB = (size_t)(n0 + rowA) * SD + kg * 8;

    const int lr = ln & 15;          // fragment row/col within 16
    const int lk = (ln >> 4) * 8;    // k-slice base

    for (int k0 = 0; k0 < SD; k0 += 32) {
        __builtin_amdgcn_global_load_lds((glb_t*)(A  + gA + k0),
            (lds_t*)((char*)As + wv * 1024), 16, 0, 0);
        __builtin_amdgcn_global_load_lds((glb_t*)(A  + gA + (size_t)64 * SD + k0),
            (lds_t*)((char*)As + 4096 + wv * 1024), 16, 0, 0);
        __builtin_amdgcn_global_load_lds((glb_t*)(BT + gB + k0),
            (lds_t*)((char*)Bs + wv * 1024), 16, 0, 0);
        __builtin_amdgcn_global_load_lds((glb_t*)(BT + gB + (size_t)64 * SD + k0),
            (lds_t*)((char*)Bs + 4096 + wv * 1024), 16, 0, 0);
        __syncthreads();   // drains vmcnt(0) before barrier (compiler-enforced)

        short8 af[4], bf_[4];
        #pragma unroll
        for (int mt = 0; mt < 4; ++mt)
            af[mt] = *(const short8*)&As[(wm + mt * 16 + lr) * 32 + lk];
        #pragma unroll
        for (int nt = 0; nt < 4; ++nt)
            bf_[nt] = *(const short8*)&Bs[(wn + nt * 16 + lr) * 32 + lk];
        #pragma unroll
        for (int mt = 0; mt < 4; ++mt)
            #pragma unroll
            for (int nt = 0; nt < 4; ++nt)
                acc[mt][nt] = __builtin_amdgcn_mfma_f32_16x16x32_bf16(
                    af[mt], bf_[nt], acc[mt][nt], 0, 0, 0);
        __syncthreads();
    }

    // epilogue: C row = (lane>>4)*4 + j, col = lane&15  (m89-verified layout)
    const int cr = (ln >> 4) * 4;
    const int cc = ln & 15;
    #pragma unroll
    for (int mt = 0; mt < 4; ++mt) {
        #pragma unroll
        for (int nt = 0; nt < 4; ++nt) {
            const int gc = n0 + wn + nt * 16 + cc;
            const float bv = bias[gc];
            #pragma unroll
            for (int j = 0; j < 4; ++j) {
                const int gr = m0 + wm + mt * 16 + cr + j;
                float v = acc[mt][nt][j] + bv;
                if (MODE == 1) v = 1.f / (1.f + __expf(-v));
                if (MODE <= 1)
                    ((ushort*)Cout)[(size_t)gr * SD + gc] = f2bf(v);
                else
                    ((float*)Cout)[(size_t)gr * SD + gc] = v;
            }
        }
    }
}

// ---------------- scan pass 1: per-chunk local states from zero init ----------------
__global__ __launch_bounds__(256)
void scan_local(const ushort* __restrict__ kq, const ushort* __restrict__ vq,
                const float* __restrict__ td,
                float* __restrict__ sa, float* __restrict__ sb, float* __restrict__ sp)
{
    const int idx = blockIdx.x * 256 + threadIdx.x;   // 8192*NC
    const int ch = idx & (M_DIM - 1);
    const int c  = idx >> 13;
    const int b  = ch >> 10, d = ch & (SD - 1);
    const float w = -__expf(td[d]);
    size_t ptr = (size_t)b * U_DIM * SD + (size_t)(c * CT) * SD + d;

    float a = 0.f, bb = 0.f, p = -1e38f;
    for (int s = 0; s < CT; ++s) {
        const float kt = bf2f(kq[ptr]), vt = bf2f(vq[ptr]);
        const float q2 = fmaxf(p + w, kt);
        const float e1 = __expf(p + w - q2);
        const float e2 = __expf(kt - q2);
        a = e1 * a + e2 * vt; bb = e1 * bb + e2; p = q2;
        ptr += SD;
    }
    sa[idx] = a; sb[idx] = bb; sp[idx] = p;
}

// ---------------- scan pass 2: sequential prefix-combine over chunks ----------------
// overwrites local states with the INCOMING prefix state for each chunk
__global__ __launch_bounds__(256)
void scan_prefix(const float* __restrict__ td,
                 float* __restrict__ sa, float* __restrict__ sb, float* __restrict__ sp)
{
    const int ch = blockIdx.x * 256 + threadIdx.x;    // 8192
    const float wT = -__expf(td[ch & (SD - 1)]) * (float)CT;
    float ca = 0.f, cb = 0.f, cp = -1e38f;
    for (int c = 0; c < NC; ++c) {
        const int i = c * M_DIM + ch;
        const float la = sa[i], lb = sb[i], lp = sp[i];
        sa[i] = ca; sb[i] = cb; sp[i] = cp;
        const float pd = cp + wT;                      // decay carry across chunk
        const float q  = fmaxf(pd, lp);
        const float e1 = __expf(pd - q);
        const float e2 = __expf(lp - q);
        ca = e1 * ca + e2 * la; cb = e1 * cb + e2 * lb; cp = q;
    }
}

// ---------------- scan pass 3: outputs r*wkv (bf16) from incoming states ----------------
__global__ __launch_bounds__(256)
void scan_out(const ushort* __restrict__ kq, const ushort* __restrict__ vq,
              const ushort* __restrict__ rq,
              const float* __restrict__ td, const float* __restrict__ tfirst,
              const float* __restrict__ sa, const float* __restrict__ sb,
              const float* __restrict__ sp,
              ushort* __restrict__ rw)
{
    const int idx = blockIdx.x * 256 + threadIdx.x;
    const int ch = idx & (M_DIM - 1);
    const int c  = idx >> 13;
    const int b  = ch >> 10, d = ch & (SD - 1);
    const float w  = -__expf(td[d]);
    const float tf = tfirst[d];
    size_t ptr = (size_t)b * U_DIM * SD + (size_t)(c * CT) * SD + d;

    float a = sa[idx], bb = sb[idx], p = sp[idx];
    for (int s = 0; s < CT; ++s) {
        const float kt = bf2f(kq[ptr]), vt = bf2f(vq[ptr]), rt = bf2f(rq[ptr]);
        // output (time_first bonus on current token)
        const float q  = fmaxf(p, tf + kt);
        const float e1 = __expf(p - q);
        const float e2 = __expf(tf + kt - q);
        const float ov = (e1 * a + e2 * vt) * __builtin_amdgcn_rcpf(e1 * bb + e2);
        // state update
        const float q2  = fmaxf(p + w, kt);
        const float e1b = __expf(p + w - q2);
        const float e2b = __expf(kt - q2);
        a = e1b * a + e2b * vt; bb = e1b * bb + e2b; p = q2;
        rw[ptr] = f2bf(rt * ov);
        ptr += SD;
    }
}

extern "C" void kernel_launch(void* const* d_in, const int* in_sizes, int n_in,
                              void* d_out, int out_size, void* d_ws, size_t ws_size,
                              hipStream_t stream)
{
    (void)in_sizes; (void)n_in; (void)out_size; (void)ws_size;
    const float* x  = (const float*)d_in[0];
    const float* td = (const float*)d_in[1];
    const float* tf = (const float*)d_in[2];
    const float* mk = (const float*)d_in[3];
    const float* mv = (const float*)d_in[4];
    const float* mr = (const float*)d_in[5];
    const float* Wk = (const float*)d_in[6];
    const float* bk = (const float*)d_in[7];
    const float* Wv = (const float*)d_in[8];
    const float* bv = (const float*)d_in[9];
    const float* Wr = (const float*)d_in[10];
    const float* br = (const float*)d_in[11];
    const float* Wo = (const float*)d_in[12];
    const float* bo = (const float*)d_in[13];
    float* out = (float*)d_out;

    // workspace layout (peak 75 MB; round-1 proved >= 96 MB available)
    char* ws = (char*)d_ws;
    ushort* WT   = (ushort*)ws;                        //  0 MB: 4 x 2 MB bf16 W^T
    ushort* Abuf = (ushort*)(ws + ((size_t)8  << 20)); //  8 MB: 16 MB (later rwkv)
    ushort* kbuf = (ushort*)(ws + ((size_t)24 << 20)); // 24 MB
    ushort* vbuf = (ushort*)(ws + ((size_t)40 << 20)); // 40 MB
    ushort* rbuf = (ushort*)(ws + ((size_t)56 << 20)); // 56 MB
    float*  sa   = (float*)(ws + ((size_t)72 << 20));  // 1 MB each
    float*  sb   = (float*)(ws + ((size_t)73 << 20));
    float*  sp   = (float*)(ws + ((size_t)74 << 20));
    ushort* rwkv = Abuf;                               // Abuf dead after GEMM-r

    wtrans_kernel<<<dim3(32, 32, 4), 256, 0, stream>>>(Wk, Wv, Wr, Wo, WT);

    const dim3 gg(M_DIM / 128, SD / 128, 1);
    mix_kernel<<<8192, 256, 0, stream>>>(x, mk, Abuf);
    gemm_bf16<0><<<gg, 256, 0, stream>>>(Abuf, WT + (size_t)0 * SD * SD, bk, kbuf);
    mix_kernel<<<8192, 256, 0, stream>>>(x, mv, Abuf);
    gemm_bf16<0><<<gg, 256, 0, stream>>>(Abuf, WT + (size_t)1 * SD * SD, bv, vbuf);
    mix_kernel<<<8192, 256, 0, stream>>>(x, mr, Abuf);
    gemm_bf16<1><<<gg, 256, 0, stream>>>(Abuf, WT + (size_t)2 * SD * SD, br, rbuf);

    scan_local <<<(M_DIM * NC) / 256, 256, 0, stream>>>(kbuf, vbuf, td, sa, sb, sp);
    scan_prefix<<<M_DIM / 256, 256, 0, stream>>>(td, sa, sb, sp);
    scan_out   <<<(M_DIM * NC) / 256, 256, 0, stream>>>(kbuf, vbuf, rbuf, td, tf,
                                                        sa, sb, sp, rwkv);

    gemm_bf16<2><<<gg, 256, 0, stream>>>(rwkv, WT + (size_t)3 * SD * SD, bo, out);
}

// Round 3
// 169.925 us; speedup vs baseline: 7.5901x; 1.0813x over previous
//
#include <hip/hip_runtime.h>
#include <cstdint>
#include <cstddef>

#define B_DIM 8
#define U_DIM 1024
#define SD    1024                 // SIZE == D_ATT == 1024
#define M_DIM (B_DIM * U_DIM)      // 8192 rows; also B*D channel count
#define NC 32                      // scan chunks
#define CT 32                      // tokens per chunk (NC*CT == U_DIM)

typedef __attribute__((ext_vector_type(8))) short short8;
typedef __attribute__((ext_vector_type(4))) float f32x4;

typedef __attribute__((address_space(3))) void       lds_t;
typedef const __attribute__((address_space(1))) void glb_t;

__device__ __forceinline__ ushort f2bf(float f) {
    union { float f; uint32_t u; } c; c.f = f;
    uint32_t r = (c.u + 0x7FFFu + ((c.u >> 16) & 1u)) >> 16;   // RNE
    return (ushort)r;
}
__device__ __forceinline__ float bf2f(ushort h) {
    union { float f; uint32_t u; } c; c.u = ((uint32_t)h) << 16; return c.f;
}

// ---------------- prepass: W[K][N] f32 -> W^T[N][K] bf16, 4 matrices ----------------
__global__ __launch_bounds__(256)
void wtrans_kernel(const float* __restrict__ Wk, const float* __restrict__ Wv,
                   const float* __restrict__ Wr, const float* __restrict__ Wo,
                   ushort* __restrict__ WT)
{
    __shared__ float t[32][33];
    const float* W = (blockIdx.z == 0) ? Wk : (blockIdx.z == 1) ? Wv
                   : (blockIdx.z == 2) ? Wr : Wo;
    ushort* o = WT + (size_t)blockIdx.z * SD * SD;
    const int tx = threadIdx.x & 31, ty = threadIdx.x >> 5;
    const int k0 = blockIdx.y * 32, n0 = blockIdx.x * 32;
    #pragma unroll
    for (int i = 0; i < 4; ++i)
        t[ty + i * 8][tx] = W[(size_t)(k0 + ty + i * 8) * SD + n0 + tx];
    __syncthreads();
    #pragma unroll
    for (int i = 0; i < 4; ++i)
        o[(size_t)(n0 + ty + i * 8) * SD + k0 + tx] = f2bf(t[tx][ty + i * 8]);
}

// ---------------- prepass: A_j = sh + mix_j*(x - sh), bf16, all three in one pass ----
__global__ __launch_bounds__(256)
void mix3_kernel(const float* __restrict__ x,
                 const float* __restrict__ mk, const float* __restrict__ mv,
                 const float* __restrict__ mr,
                 ushort* __restrict__ Ak, ushort* __restrict__ Av,
                 ushort* __restrict__ Ar)
{
    const int idx = blockIdx.x * 256 + threadIdx.x;  // 2M groups of 4
    const int m = idx >> 8;
    const int s = (idx & 255) << 2;
    const float4 xv = *(const float4*)&x[(size_t)m * SD + s];
    float4 sh = make_float4(0.f, 0.f, 0.f, 0.f);
    if (m & (U_DIM - 1)) sh = *(const float4*)&x[(size_t)(m - 1) * SD + s];
    const float4 dx = make_float4(xv.x - sh.x, xv.y - sh.y, xv.z - sh.z, xv.w - sh.w);
    const size_t off = (size_t)m * SD + s;

    float4 mx;
    ushort4 o;
    mx = *(const float4*)&mk[s];
    o.x = f2bf(sh.x + mx.x * dx.x); o.y = f2bf(sh.y + mx.y * dx.y);
    o.z = f2bf(sh.z + mx.z * dx.z); o.w = f2bf(sh.w + mx.w * dx.w);
    *(ushort4*)&Ak[off] = o;
    mx = *(const float4*)&mv[s];
    o.x = f2bf(sh.x + mx.x * dx.x); o.y = f2bf(sh.y + mx.y * dx.y);
    o.z = f2bf(sh.z + mx.z * dx.z); o.w = f2bf(sh.w + mx.w * dx.w);
    *(ushort4*)&Av[off] = o;
    mx = *(const float4*)&mr[s];
    o.x = f2bf(sh.x + mx.x * dx.x); o.y = f2bf(sh.y + mx.y * dx.y);
    o.z = f2bf(sh.z + mx.z * dx.z); o.w = f2bf(sh.w + mx.w * dx.w);
    *(ushort4*)&Ar[off] = o;
}

// ---------------- single-projection mix (fallback path) ----------------
__global__ __launch_bounds__(256)
void mix_kernel(const float* __restrict__ x, const float* __restrict__ mix,
                ushort* __restrict__ outA)
{
    const int idx = blockIdx.x * 256 + threadIdx.x;
    const int m = idx >> 8;
    const int s = (idx & 255) << 2;
    const float4 xv = *(const float4*)&x[(size_t)m * SD + s];
    float4 sh = make_float4(0.f, 0.f, 0.f, 0.f);
    if (m & (U_DIM - 1)) sh = *(const float4*)&x[(size_t)(m - 1) * SD + s];
    const float4 mx = *(const float4*)&mix[s];
    ushort4 o;
    o.x = f2bf(sh.x + mx.x * (xv.x - sh.x));
    o.y = f2bf(sh.y + mx.y * (xv.y - sh.y));
    o.z = f2bf(sh.z + mx.z * (xv.z - sh.z));
    o.w = f2bf(sh.w + mx.w * (xv.w - sh.w));
    *(ushort4*)&outA[(size_t)m * SD + s] = o;
}

// ---------------- bf16 MFMA GEMM, 2-phase double-buffered, swizzled LDS ----------------
// FUSED==3: grid.z in {0,1,2} selects {k,v,r} (A/BT/bias per z; sigmoid at z==2), bf16 out
// FUSED==0: single GEMM, bf16 out          FUSED==1: single, bf16 out + sigmoid
// FUSED==2: single GEMM, f32 out
// C[M,N] = A[M,K] @ (BT[N,K])^T + bias
template<int FUSED>
__global__ __launch_bounds__(256)
void gemm_bf16(const ushort* __restrict__ Abase, const ushort* __restrict__ WT,
               const float* __restrict__ b0, const float* __restrict__ b1,
               const float* __restrict__ b2, void* __restrict__ Cbase)
{
    __shared__ ushort As[2][4096];   // [buf][128 rows x 32 k], row stride 64B
    __shared__ ushort Bs[2][4096];

    const int tid = threadIdx.x;
    const int wv = tid >> 6, ln = tid & 63;
    const int m0 = blockIdx.x * 128, n0 = blockIdx.y * 128;
    const int wm = (wv >> 1) * 64, wn = (wv & 1) * 64;

    const ushort* A; const ushort* BT; const float* bias; void* Cout; int dosig;
    if (FUSED == 3) {
        const int z = blockIdx.z;
        A    = Abase + (size_t)z * ((size_t)M_DIM * SD);
        BT   = WT + (size_t)z * ((size_t)SD * SD);
        bias = (z == 0) ? b0 : (z == 1) ? b1 : b2;
        Cout = (void*)((ushort*)Cbase + (size_t)z * ((size_t)M_DIM * SD));
        dosig = (z == 2);
    } else {
        A = Abase; BT = WT; bias = b0; Cout = Cbase; dosig = (FUSED == 1);
    }

    // ---- staging map (linear LDS dest, inverse-swizzled global source) ----
    // LDS 16B chunk index c = tid : row = c>>2, q = c&3 ; source q' = q ^ ((row>>1)&3)
    const int srow = tid >> 2;
    const int sq   = tid & 3;
    const int sqs  = sq ^ ((srow >> 1) & 3);
    const size_t gA = (size_t)(m0 + srow) * SD + sqs * 8;
    const size_t gB = (size_t)(n0 + srow) * SD + sqs * 8;
    char* const asb = (char*)As + wv * 1024;
    char* const bsb = (char*)Bs + wv * 1024;

    // ---- fragment read map (swizzled) ----
    const int lr  = ln & 15;          // fragment row within 16
    const int lq  = ln >> 4;          // k-chunk 0..3
    const int sqr = (lr >> 1) & 3;    // swizzle term: row = wm+mt*16+lr -> (row>>1)&3 == (lr>>1)&3
    const int kof = (lq ^ sqr) * 8;

    f32x4 acc[4][4];
    #pragma unroll
    for (int i = 0; i < 4; ++i)
        #pragma unroll
        for (int j = 0; j < 4; ++j)
            acc[i][j] = (f32x4){0.f, 0.f, 0.f, 0.f};

#define STAGE(buf, k0)                                                              \
    do {                                                                            \
        __builtin_amdgcn_global_load_lds((glb_t*)(A + gA + (k0)),                   \
            (lds_t*)(asb + (buf) * 8192), 16, 0, 0);                                \
        __builtin_amdgcn_global_load_lds((glb_t*)(A + gA + (size_t)64 * SD + (k0)), \
            (lds_t*)(asb + (buf) * 8192 + 4096), 16, 0, 0);                         \
        __builtin_amdgcn_global_load_lds((glb_t*)(BT + gB + (k0)),                  \
            (lds_t*)(bsb + (buf) * 8192), 16, 0, 0);                                \
        __builtin_amdgcn_global_load_lds((glb_t*)(BT + gB + (size_t)64 * SD + (k0)),\
            (lds_t*)(bsb + (buf) * 8192 + 4096), 16, 0, 0);                         \
    } while (0)

#define COMPUTE(buf)                                                                \
    do {                                                                            \
        short8 af[4], bfr[4];                                                       \
        _Pragma("unroll")                                                           \
        for (int mt = 0; mt < 4; ++mt)                                              \
            af[mt] = *(const short8*)&As[buf][(wm + mt * 16 + lr) * 32 + kof];      \
        _Pragma("unroll")                                                           \
        for (int nt = 0; nt < 4; ++nt)                                              \
            bfr[nt] = *(const short8*)&Bs[buf][(wn + nt * 16 + lr) * 32 + kof];     \
        _Pragma("unroll")                                                           \
        for (int mt = 0; mt < 4; ++mt)                                              \
            _Pragma("unroll")                                                       \
            for (int nt = 0; nt < 4; ++nt)                                          \
                acc[mt][nt] = __builtin_amdgcn_mfma_f32_16x16x32_bf16(              \
                    af[mt], bfr[nt], acc[mt][nt], 0, 0, 0);                         \
    } while (0)

    // prologue: stage tile 0
    STAGE(0, 0);
    __syncthreads();
    // steady state: prefetch t+1 while computing t; one barrier per K-step
    for (int t = 0; t < 30; t += 2) {
        STAGE(1, (size_t)(t + 1) * 32);
        COMPUTE(0);
        __syncthreads();
        STAGE(0, (size_t)(t + 2) * 32);
        COMPUTE(1);
        __syncthreads();
    }
    STAGE(1, (size_t)31 * 32);
    COMPUTE(0);
    __syncthreads();
    COMPUTE(1);

#undef STAGE
#undef COMPUTE

    // ---- epilogue: C row = (lane>>4)*4 + j, col = lane&15 (m89-verified) ----
    const int cr = (ln >> 4) * 4;
    const int cc = ln & 15;
    #pragma unroll
    for (int mt = 0; mt < 4; ++mt) {
        #pragma unroll
        for (int nt = 0; nt < 4; ++nt) {
            const int gc = n0 + wn + nt * 16 + cc;
            const float bv = bias[gc];
            #pragma unroll
            for (int j = 0; j < 4; ++j) {
                const int gr = m0 + wm + mt * 16 + cr + j;
                float v = acc[mt][nt][j] + bv;
                if (FUSED == 1 || FUSED == 3) {
                    if (dosig) v = 1.f / (1.f + __expf(-v));
                }
                if (FUSED == 2)
                    ((float*)Cout)[(size_t)gr * SD + gc] = v;
                else
                    ((ushort*)Cout)[(size_t)gr * SD + gc] = f2bf(v);
            }
        }
    }
}

// ---------------- scan pass 1: per-chunk local states from zero init ----------------
__global__ __launch_bounds__(256)
void scan_local(const ushort* __restrict__ kq, const ushort* __restrict__ vq,
                const float* __restrict__ td,
                float* __restrict__ sa, float* __restrict__ sb, float* __restrict__ sp)
{
    const int idx = blockIdx.x * 256 + threadIdx.x;   // 8192*NC
    const int ch = idx & (M_DIM - 1);
    const int c  = idx >> 13;
    const int b  = ch >> 10, d = ch & (SD - 1);
    const float w = -__expf(td[d]);
    size_t ptr = (size_t)b * U_DIM * SD + (size_t)(c * CT) * SD + d;

    float a = 0.f, bb = 0.f, p = -1e38f;
    for (int s = 0; s < CT; ++s) {
        const float kt = bf2f(kq[ptr]), vt = bf2f(vq[ptr]);
        const float q2 = fmaxf(p + w, kt);
        const float e1 = __expf(p + w - q2);
        const float e2 = __expf(kt - q2);
        a = e1 * a + e2 * vt; bb = e1 * bb + e2; p = q2;
        ptr += SD;
    }
    sa[idx] = a; sb[idx] = bb; sp[idx] = p;
}

// ---------------- scan pass 2: sequential prefix-combine over chunks ----------------
__global__ __launch_bounds__(256)
void scan_prefix(const float* __restrict__ td,
                 float* __restrict__ sa, float* __restrict__ sb, float* __restrict__ sp)
{
    const int ch = blockIdx.x * 256 + threadIdx.x;    // 8192
    const float wT = -__expf(td[ch & (SD - 1)]) * (float)CT;
    float ca = 0.f, cb = 0.f, cp = -1e38f;
    for (int c = 0; c < NC; ++c) {
        const int i = c * M_DIM + ch;
        const float la = sa[i], lb = sb[i], lp = sp[i];
        sa[i] = ca; sb[i] = cb; sp[i] = cp;
        const float pd = cp + wT;                      // decay carry across chunk
        const float q  = fmaxf(pd, lp);
        const float e1 = __expf(pd - q);
        const float e2 = __expf(lp - q);
        ca = e1 * ca + e2 * la; cb = e1 * cb + e2 * lb; cp = q;
    }
}

// ---------------- scan pass 3: outputs r*wkv (bf16) from incoming states ----------------
__global__ __launch_bounds__(256)
void scan_out(const ushort* __restrict__ kq, const ushort* __restrict__ vq,
              const ushort* __restrict__ rq,
              const float* __restrict__ td, const float* __restrict__ tfirst,
              const float* __restrict__ sa, const float* __restrict__ sb,
              const float* __restrict__ sp,
              ushort* __restrict__ rw)
{
    const int idx = blockIdx.x * 256 + threadIdx.x;
    const int ch = idx & (M_DIM - 1);
    const int c  = idx >> 13;
    const int b  = ch >> 10, d = ch & (SD - 1);
    const float w  = -__expf(td[d]);
    const float tf = tfirst[d];
    size_t ptr = (size_t)b * U_DIM * SD + (size_t)(c * CT) * SD + d;

    float a = sa[idx], bb = sb[idx], p = sp[idx];
    for (int s = 0; s < CT; ++s) {
        const float kt = bf2f(kq[ptr]), vt = bf2f(vq[ptr]), rt = bf2f(rq[ptr]);
        const float q  = fmaxf(p, tf + kt);
        const float e1 = __expf(p - q);
        const float e2 = __expf(tf + kt - q);
        const float ov = (e1 * a + e2 * vt) * __builtin_amdgcn_rcpf(e1 * bb + e2);
        const float q2  = fmaxf(p + w, kt);
        const float e1b = __expf(p + w - q2);
        const float e2b = __expf(kt - q2);
        a = e1b * a + e2b * vt; bb = e1b * bb + e2b; p = q2;
        rw[ptr] = f2bf(rt * ov);
        ptr += SD;
    }
}

extern "C" void kernel_launch(void* const* d_in, const int* in_sizes, int n_in,
                              void* d_out, int out_size, void* d_ws, size_t ws_size,
                              hipStream_t stream)
{
    (void)in_sizes; (void)n_in; (void)out_size;
    const float* x  = (const float*)d_in[0];
    const float* td = (const float*)d_in[1];
    const float* tf = (const float*)d_in[2];
    const float* mk = (const float*)d_in[3];
    const float* mv = (const float*)d_in[4];
    const float* mr = (const float*)d_in[5];
    const float* Wk = (const float*)d_in[6];
    const float* bk = (const float*)d_in[7];
    const float* Wv = (const float*)d_in[8];
    const float* bv = (const float*)d_in[9];
    const float* Wr = (const float*)d_in[10];
    const float* br = (const float*)d_in[11];
    const float* Wo = (const float*)d_in[12];
    const float* bo = (const float*)d_in[13];
    float* out = (float*)d_out;

    const size_t NE = (size_t)M_DIM * SD;   // 8M elements
    char* ws = (char*)d_ws;

    const dim3 gg1(M_DIM / 128, SD / 128, 1);
    const dim3 gg3(M_DIM / 128, SD / 128, 3);

    if (ws_size >= ((size_t)108 << 20)) {
        // -------- fused layout: WT 0-8 | Ak 8-24 | Av 24-40 | Ar 40-56 |
        //          k 56-72 | v 72-88 | r 88-104 | states 104-107  (MB)
        ushort* WT  = (ushort*)ws;
        ushort* Ak  = (ushort*)(ws + ((size_t)8   << 20));
        ushort* kvr = (ushort*)(ws + ((size_t)56  << 20));
        float*  sa  = (float*)(ws + ((size_t)104 << 20));
        float*  sb  = (float*)(ws + ((size_t)105 << 20));
        float*  sp  = (float*)(ws + ((size_t)106 << 20));
        ushort* kbuf = kvr;
        ushort* vbuf = kvr + NE;
        ushort* rbuf = kvr + 2 * NE;
        ushort* rwkv = Ak;                  // A-buffers dead after proj GEMM

        wtrans_kernel<<<dim3(32, 32, 4), 256, 0, stream>>>(Wk, Wv, Wr, Wo, WT);
        mix3_kernel<<<8192, 256, 0, stream>>>(x, mk, mv, mr, Ak, Ak + NE, Ak + 2 * NE);
        gemm_bf16<3><<<gg3, 256, 0, stream>>>(Ak, WT, bk, bv, br, kvr);

        scan_local <<<(M_DIM * NC) / 256, 256, 0, stream>>>(kbuf, vbuf, td, sa, sb, sp);
        scan_prefix<<<M_DIM / 256, 256, 0, stream>>>(td, sa, sb, sp);
        scan_out   <<<(M_DIM * NC) / 256, 256, 0, stream>>>(kbuf, vbuf, rbuf, td, tf,
                                                            sa, sb, sp, rwkv);

        gemm_bf16<2><<<gg1, 256, 0, stream>>>(rwkv, WT + 3 * NE / 8, bo, bo, bo, out);
        // note: WT matrices are SD*SD = 1M elems each; 3rd index = WT + 3*1M
    } else {
        // -------- sequential layout (75 MB, round-2 proven) --------
        ushort* WT   = (ushort*)ws;
        ushort* Abuf = (ushort*)(ws + ((size_t)8  << 20));
        ushort* kbuf = (ushort*)(ws + ((size_t)24 << 20));
        ushort* vbuf = (ushort*)(ws + ((size_t)40 << 20));
        ushort* rbuf = (ushort*)(ws + ((size_t)56 << 20));
        float*  sa   = (float*)(ws + ((size_t)72 << 20));
        float*  sb   = (float*)(ws + ((size_t)73 << 20));
        float*  sp   = (float*)(ws + ((size_t)74 << 20));
        ushort* rwkv = Abuf;
        const size_t WS = (size_t)SD * SD;

        wtrans_kernel<<<dim3(32, 32, 4), 256, 0, stream>>>(Wk, Wv, Wr, Wo, WT);
        mix_kernel<<<8192, 256, 0, stream>>>(x, mk, Abuf);
        gemm_bf16<0><<<gg1, 256, 0, stream>>>(Abuf, WT, bk, bk, bk, kbuf);
        mix_kernel<<<8192, 256, 0, stream>>>(x, mv, Abuf);
        gemm_bf16<0><<<gg1, 256, 0, stream>>>(Abuf, WT + WS, bv, bv, bv, vbuf);
        mix_kernel<<<8192, 256, 0, stream>>>(x, mr, Abuf);
        gemm_bf16<1><<<gg1, 256, 0, stream>>>(Abuf, WT + 2 * WS, br, br, br, rbuf);

        scan_local <<<(M_DIM * NC) / 256, 256, 0, stream>>>(kbuf, vbuf, td, sa, sb, sp);
        scan_prefix<<<M_DIM / 256, 256, 0, stream>>>(td, sa, sb, sp);
        scan_out   <<<(M_DIM * NC) / 256, 256, 0, stream>>>(kbuf, vbuf, rbuf, td, tf,
                                                            sa, sb, sp, rwkv);

        gemm_bf16<2><<<gg1, 256, 0, stream>>>(rwkv, WT + 3 * WS, bo, bo, bo, out);
    }
}